// Round 8
// baseline (194.539 us; speedup 1.0000x reference)
//
#include <hip/hip_runtime.h>
#include <math.h>

#define BB 512
#define SS 128
#define KK 4
#define HH 128
#define DD 512   // K*H

typedef __attribute__((ext_vector_type(8))) short bf16x8;
typedef __attribute__((ext_vector_type(4))) float f32x4;

__device__ __forceinline__ unsigned short f2bf(float f) {
  unsigned u = __float_as_uint(f);
  unsigned r = u + 0x7fffu + ((u >> 16) & 1u);   // RNE (no NaNs in this data)
  return (unsigned short)(r >> 16);
}
__device__ __forceinline__ ushort4 f2bf4(float4 v) {
  ushort4 o; o.x = f2bf(v.x); o.y = f2bf(v.y); o.z = f2bf(v.z); o.w = f2bf(v.w);
  return o;
}
__device__ __forceinline__ float bfhi(unsigned u) { return __uint_as_float(u & 0xffff0000u); }
__device__ __forceinline__ float bflo(unsigned u) { return __uint_as_float(u << 16); }

// ---------------------------------------------------------------------------
// hat[b][k][s][h'] = sum_h item[b][s][h] * w[s][k*HH+h'][h]
// EXACT R5-verified kernel (45.9 µs): A tile staged to LDS once (bf16, XOR
// granules), 8 pipelined W-stage steps with register prefetch into
// double-buffered Wl. hat written LINEAR.
// ---------------------------------------------------------------------------
__global__ __launch_bounds__(256) void einsum_mfma(
    const float* __restrict__ item,   // f32 [B][S][H]
    const float* __restrict__ w,      // f32 [S][D][H]
    unsigned short* __restrict__ hat) // bf16 [B][K][S][H], linear
{
  __shared__ unsigned short Al[128 * 128];     // 32 KB: rows = local b, 128 h
  __shared__ unsigned short Wl[2][128 * 64];   // 2 x 16 KB K-half buffers
  const int s  = blockIdx.x;
  const int b0 = blockIdx.y * 128;
  const int t  = threadIdx.x;
  const int lane = t & 63, wvq = t >> 6;
  const int qm = wvq & 1, qn = wvq >> 1;
  const int n16 = lane & 15, kq = lane >> 4;

  const float* Abase = item + ((size_t)b0 * SS + s) * HH;  // + r*(SS*HH)
  const float* Wbase = w + (size_t)s * DD * HH;            // + (d0+r)*HH

  // ---- prologue: issue A tile + W step-0 loads, convert, park ----
  const int ac = t & 31, ar0 = t >> 5;     // A: f4-col 0..31, row base 0..7
  const int wc = t & 15, wr0 = t >> 4;     // W: f4-col 0..15, row base 0..15
  float4 apre[16];
  #pragma unroll
  for (int j = 0; j < 16; ++j)
    apre[j] = *(const float4*)(Abase + (size_t)(ar0 + 8 * j) * (SS * HH) + ac * 4);
  float4 wpre[8];
  #pragma unroll
  for (int j = 0; j < 8; ++j)
    wpre[j] = *(const float4*)(Wbase + (size_t)(wr0 + 16 * j) * HH + wc * 4);

  #pragma unroll
  for (int j = 0; j < 16; ++j) {
    const int r = ar0 + 8 * j;
    const int lg = ac >> 1;                          // logical 16B granule 0..15
    *(ushort4*)&Al[r * 128 + ((lg ^ (r & 15)) * 8) + (ac & 1) * 4] = f2bf4(apre[j]);
  }
  #pragma unroll
  for (int j = 0; j < 8; ++j) {
    const int r = wr0 + 16 * j;
    *(ushort4*)&Wl[0][r * 64 + ((((wc >> 1) + r) & 7) * 8) + (wc & 1) * 4] = f2bf4(wpre[j]);
  }
  __syncthreads();

  int buf = 0;
  for (int dt = 0; dt < 4; ++dt) {
    f32x4 acc[4][4] = {};
    #pragma unroll
    for (int hs = 0; hs < 2; ++hs) {
      const int step = dt * 2 + hs;
      if (step < 7) {                                // issue next stage EARLY
        const int d0n = ((step + 1) >> 1) * 128;
        const int ksn = ((step + 1) & 1) * 64;
        #pragma unroll
        for (int j = 0; j < 8; ++j)
          wpre[j] = *(const float4*)(Wbase + (size_t)(d0n + wr0 + 16 * j) * HH + ksn + wc * 4);
      }
      #pragma unroll
      for (int kk = 0; kk < 2; ++kk) {
        bf16x8 af[4], bfr[4];
        #pragma unroll
        for (int i = 0; i < 4; ++i) {
          const int ra = qm * 64 + i * 16 + n16;     // w rows (h')
          const int rb = qn * 64 + i * 16 + n16;     // item rows (b)
          af[i]  = *(const bf16x8*)&Wl[buf][ra * 64 + ((kk * 4 + kq + ra) & 7) * 8];
          bfr[i] = *(const bf16x8*)&Al[rb * 128 + (((hs * 8 + kk * 4 + kq) ^ (rb & 15)) * 8)];
        }
        #pragma unroll
        for (int i = 0; i < 4; ++i)
          #pragma unroll
          for (int j = 0; j < 4; ++j)
            acc[i][j] = __builtin_amdgcn_mfma_f32_16x16x32_bf16(af[i], bfr[j], acc[i][j], 0, 0, 0);
      }
      if (step < 7) {                                // write LATE, one barrier
        #pragma unroll
        for (int j = 0; j < 8; ++j) {
          const int r = wr0 + 16 * j;
          *(ushort4*)&Wl[buf ^ 1][r * 64 + ((((wc >> 1) + r) & 7) * 8) + (wc & 1) * 4] = f2bf4(wpre[j]);
        }
        __syncthreads();
        buf ^= 1;
      }
    }
    // epilogue d-tile dt: row = qm*64+i*16+kq*4+reg = h'; col = qn*64+j*16+n16 = b
    #pragma unroll
    for (int j = 0; j < 4; ++j) {
      const int b = b0 + qn * 64 + j * 16 + n16;
      unsigned short* orow = hat + (((size_t)b * KK + dt) * SS + s) * HH;
      #pragma unroll
      for (int i = 0; i < 4; ++i) {
        const int h = qm * 64 + i * 16 + kq * 4;
        ushort4 o;
        o.x = f2bf(acc[i][j][0]); o.y = f2bf(acc[i][j][1]);
        o.z = f2bf(acc[i][j][2]); o.w = f2bf(acc[i][j][3]);
        *(ushort4*)(orow + h) = o;                   // LINEAR
      }
    }
  }
}

// ---------------------------------------------------------------------------
// Batch-axis softmax (legacy torch dim=0) + mask zeroing. Grid (S,K).
// R5-verified math; ONLY change: output layout is now [B][K][S] so the
// 64-thread routing kernel reads its 128 weights as coalesced float2.
// ---------------------------------------------------------------------------
__global__ __launch_bounds__(256) void softmax_k(
    const float* __restrict__ cw,     // [K][S][B]
    const float* __restrict__ mask,   // [B][S]
    float* __restrict__ sw)           // [B][K][S]
{
  __shared__ float rbuf[4];
  const int s = blockIdx.x, k = blockIdx.y, t = threadIdx.x;
  const size_t base = ((size_t)k * SS + s) * BB;
  float v0 = cw[base + t], v1 = cw[base + 256 + t];
  float m = fmaxf(v0, v1);
  #pragma unroll
  for (int o = 32; o; o >>= 1) m = fmaxf(m, __shfl_xor(m, o));
  if ((t & 63) == 0) rbuf[t >> 6] = m;
  __syncthreads();
  m = fmaxf(fmaxf(rbuf[0], rbuf[1]), fmaxf(rbuf[2], rbuf[3]));
  float e0 = expf(v0 - m), e1 = expf(v1 - m);
  float ssum = e0 + e1;
  #pragma unroll
  for (int o = 32; o; o >>= 1) ssum += __shfl_xor(ssum, o);
  __syncthreads();
  if ((t & 63) == 0) rbuf[t >> 6] = ssum;
  __syncthreads();
  float inv = 1.f / (rbuf[0] + rbuf[1] + rbuf[2] + rbuf[3]);
  float m0 = mask[(size_t)t * SS + s];
  float m1 = mask[(size_t)(t + 256) * SS + s];
  sw[(size_t)t * (KK * SS) + k * SS + s]         = (m0 == 0.f) ? 0.f : e0 * inv;
  sw[(size_t)(t + 256) * (KK * SS) + k * SS + s] = (m1 == 0.f) ? 0.f : e1 * inv;
}

// ---------------------------------------------------------------------------
// Routing iteration, REGISTER-SLAB version (bisection of the R6/R7 fused
// failure INTO the passing split pipeline): block = 1 wave = one (b,k);
// lane l holds hat[s][2l..2l+1] for all 128 s in 128 VGPRs (all indices
// compile-time static). No 32 KB LDS slab, no DMA wait: the 64 MB hat read
// is a pure TLP-streamed coalesced load at 8 blocks/CU.
// Phase 2 uses the red[32][65] transpose-reduce (re-derived; 2-way-bank
// free). cw semantics identical to R5: mode0 store, mode1 RMW.
//   mode 0: uniform sw from mask, cw  = delta
//   mode 1: sw from sw_in,        cw += delta
//   mode 2: sw from sw_in,        out = squash(cap)
// ---------------------------------------------------------------------------
__global__ __launch_bounds__(64, 2) void routing_k(
    const unsigned short* __restrict__ hat,  // bf16 [B][K][S][H]
    const float* __restrict__ mask,          // [B][S]
    const float* __restrict__ sw_in,         // [B][K][S]
    float* __restrict__ cw,                  // [K][S][B]
    float* __restrict__ out, int mode)       // [B][K][H]
{
  __shared__ float sw_l[128];
  __shared__ float red[32][65];              // +1 pad: 2-way banks (free)
  const int b = blockIdx.x, k = blockIdx.y;
  const int l = threadIdx.x;

  // slab -> registers: lane l holds hp[s] = hat[b][k][s][2l | 2l+1<<16]
  const unsigned* slab = (const unsigned*)(hat + ((size_t)(b * KK + k) * SS) * HH);
  unsigned hp[128];
  #pragma unroll
  for (int s = 0; s < 128; ++s) hp[s] = slab[s * 64 + l];

  // sw for this iteration
  if (mode == 0) {
    float2 mv = ((const float2*)(mask + (size_t)b * SS))[l];
    sw_l[2 * l]     = (mv.x == 0.f) ? 0.f : (1.f / 512.f);
    sw_l[2 * l + 1] = (mv.y == 0.f) ? 0.f : (1.f / 512.f);
  } else {
    float2 sv = ((const float2*)(sw_in + ((size_t)b * KK + k) * SS))[l];
    sw_l[2 * l] = sv.x; sw_l[2 * l + 1] = sv.y;
  }
  __syncthreads();

  // phase 1: cap[2l], cap[2l+1] = sum_s sw[s]*hat[s][2l..2l+1]
  float c0 = 0.f, c1 = 0.f;
  #pragma unroll
  for (int s = 0; s < 128; ++s) {
    float wv = sw_l[s];
    c0 = fmaf(wv, bflo(hp[s]), c0);
    c1 = fmaf(wv, bfhi(hp[s]), c1);
  }
  // squash
  float sq = c0 * c0 + c1 * c1;
  #pragma unroll
  for (int o = 32; o; o >>= 1) sq += __shfl_xor(sq, o);
  const float fac = sq / (1.f + sq) / sqrtf(sq + 1e-9f);
  c0 *= fac; c1 *= fac;

  if (mode == 2) {
    ((float2*)(out + ((size_t)b * KK + k) * HH))[l] = make_float2(c0, c1);
    return;
  }

  // phase 2: delta[s] = sum_h hat[s][h]*cap[h], via 32x64 LDS transpose.
  // red[j][l] = lane l's 2-element contribution for s = c*32+j; lane pair
  // (2j, 2j+1) then sums columns [0..31] / [32..63] of row j and combines.
  #pragma unroll
  for (int c = 0; c < 4; ++c) {
    #pragma unroll
    for (int j = 0; j < 32; ++j) {
      const int s = c * 32 + j;
      red[j][l] = fmaf(bflo(hp[s]), c0, bfhi(hp[s]) * c1);
    }
    __syncthreads();
    const int sp = l >> 1, half = l & 1;
    float dsum = 0.f;
    #pragma unroll
    for (int q = 0; q < 32; ++q) dsum += red[sp][half * 32 + q];
    dsum += __shfl_xor(dsum, 1);
    if (half == 0) {
      float* p = cw + ((size_t)k * SS + c * 32 + sp) * BB + b;
      if (mode == 0) *p = dsum; else *p += dsum;
    }
    __syncthreads();
  }
}

extern "C" void kernel_launch(void* const* d_in, const int* in_sizes, int n_in,
                              void* d_out, int out_size, void* d_ws, size_t ws_size,
                              hipStream_t stream) {
  const float* item_eb = (const float*)d_in[0];   // [B,S,H]
  const float* mask    = (const float*)d_in[1];   // [B,S]
  const float* w       = (const float*)d_in[2];   // [1,S,K*H,H]
  float* out = (float*)d_out;                     // [B,K,H]

  char* ws = (char*)d_ws;
  unsigned short* hat_bf = (unsigned short*)ws;        // 67.1 MB [B][K][S][H]
  float* cw  = (float*)(ws + 67108864);                // 1 MB [K][S][B]
  float* swb = (float*)(ws + 68157440);                // 1 MB [B][K][S]

  einsum_mfma<<<dim3(128, 4), 256, 0, stream>>>(item_eb, w, hat_bf);

  routing_k<<<dim3(BB, KK), 64, 0, stream>>>(hat_bf, mask, nullptr, cw, out, 0);
  softmax_k<<<dim3(SS, KK), 256, 0, stream>>>(cw, mask, swb);
  routing_k<<<dim3(BB, KK), 64, 0, stream>>>(hat_bf, mask, swb, cw, out, 1);
  softmax_k<<<dim3(SS, KK), 256, 0, stream>>>(cw, mask, swb);
  routing_k<<<dim3(BB, KK), 64, 0, stream>>>(hat_bf, mask, swb, cw, out, 2);
}